// Round 3
// baseline (523.371 us; speedup 1.0000x reference)
//
#include <hip/hip_runtime.h>
#include <cstdint>
#include <cstddef>

typedef float v4f __attribute__((ext_vector_type(4)));
typedef short short8 __attribute__((ext_vector_type(8)));
typedef unsigned short ushort_t;

constexpr int B_ = 8, P_ = 16384, Q_ = 256, E_ = 128;

// ---------- helpers ----------
__device__ __forceinline__ unsigned int f2bf(float f) {
  unsigned int x = __float_as_uint(f);
  x += 0x7FFFu + ((x >> 16) & 1u);           // round-to-nearest-even
  return x >> 16;
}
__device__ __forceinline__ float softplus_f(float x) {
  return fmaxf(x, 0.f) + __logf(1.f + __expf(-fabsf(x)));
}
__device__ __forceinline__ void gload16(const void* g, void* l) {
  __builtin_amdgcn_global_load_lds((const __attribute__((address_space(1))) void*)g,
                                   (__attribute__((address_space(3))) void*)l,
                                   16, 0, 0);
}

// ---------- P1: row pass + transpose via col-major LDS staging ----------
// Global layout (unchanged from r2): A1T/PPT[b][cp][q][64p] bf16, 16B chunk gc
// holds LDS pair-chunk cc = gc ^ (q&7).  Staging: st[ppair*260 + q] (pair-packed
// bf16 words), filled with contiguous ds_write_b128 (conflict-free).
__global__ __launch_bounds__(256, 4) void prep_rows(
    const float* __restrict__ mlv, const int* __restrict__ mask,
    ushort_t* __restrict__ A1T, ushort_t* __restrict__ PPT,
    float* __restrict__ negsum, float* __restrict__ ppsum)
{
  __shared__ unsigned int st[32 * 260];   // 33.3 KB
  const int t = threadIdx.x, w = t >> 6, l = t & 63;
  const int b = blockIdx.x >> 8, cp = blockIdx.x & 255;
  const size_t base = ((size_t)b * P_ + (size_t)cp * 64) * Q_;
  const float* rbase = mlv + base + (size_t)(w * 16) * Q_ + 4 * l;
  const int*   mbase = mask + base + (size_t)(w * 16) * Q_ + 4 * l;
  float accN[4] = {0.f,0.f,0.f,0.f}, accP[4] = {0.f,0.f,0.f,0.f};
  uint4 ppw[8];

  float4 X0 = *(const float4*)(rbase);
  float4 X1 = *(const float4*)(rbase + Q_);
  int4   M0 = *(const int4*)(mbase);
  int4   M1 = *(const int4*)(mbase + Q_);
#pragma unroll
  for (int m = 0; m < 8; ++m) {
    const int nm = (m < 7) ? m + 1 : 7;
    float4 nX0 = *(const float4*)(rbase + (2 * nm) * Q_);
    float4 nX1 = *(const float4*)(rbase + (2 * nm + 1) * Q_);
    int4   nM0 = *(const int4*)(mbase + (2 * nm) * Q_);
    int4   nM1 = *(const int4*)(mbase + (2 * nm + 1) * Q_);
    const float xs0[4] = {X0.x, X0.y, X0.z, X0.w};
    const float xs1[4] = {X1.x, X1.y, X1.z, X1.w};
    const int   ms0[4] = {M0.x, M0.y, M0.z, M0.w};
    const int   ms1[4] = {M1.x, M1.y, M1.z, M1.w};
    float e0[4], e1[4]; float s0 = 0.f, s1 = 0.f;
    unsigned int a1w[4];
#pragma unroll
    for (int j = 0; j < 4; ++j) {
      const bool q0 = ms0[j] != 0, q1 = ms1[j] != 0;
      const float ev0 = q0 ? __expf(xs0[j]) : 0.f;
      const float ev1 = q1 ? __expf(xs1[j]) : 0.f;
      e0[j] = ev0; e1[j] = ev1; s0 += ev0; s1 += ev1;
      accN[j] += __logf(1.f + ev0) + __logf(1.f + ev1);   // softplus(x) on masked
      a1w[j] = f2bf(q0 ? -xs0[j] : 0.f) | (f2bf(q1 ? -xs1[j] : 0.f) << 16);
    }
#pragma unroll
    for (int o = 32; o; o >>= 1) { s0 += __shfl_xor(s0, o, 64); s1 += __shfl_xor(s1, o, 64); }
    const float i0 = (s0 > 0.f) ? (1.f / s0) : 0.f;
    const float i1 = (s1 > 0.f) ? (1.f / s1) : 0.f;
    unsigned int pw[4];
#pragma unroll
    for (int j = 0; j < 4; ++j) {
      const float p0 = e0[j] * i0, p1 = e1[j] * i1;
      accP[j] += p0 + p1;
      pw[j] = f2bf(p0) | (f2bf(p1) << 16);
    }
    ppw[m].x = pw[0]; ppw[m].y = pw[1]; ppw[m].z = pw[2]; ppw[m].w = pw[3];
    uint4 av; av.x = a1w[0]; av.y = a1w[1]; av.z = a1w[2]; av.w = a1w[3];
    *(uint4*)(st + (w * 8 + m) * 260 + 4 * l) = av;       // contiguous b128, conflict-free
    X0 = nX0; X1 = nX1; M0 = nM0; M1 = nM1;
  }
  const size_t tb = ((size_t)(b * 256 + cp)) * 16384;
  __syncthreads();
  {
    uint4* dst = (uint4*)(A1T + tb);
#pragma unroll
    for (int pass = 0; pass < 8; ++pass) {
      const int gi = pass * 256 + t;
      const int q = gi >> 3, cc = (gi & 7) ^ (q & 7);
      const int wb = cc * 1040 + q;                       // (cc*4+i)*260 + q
      uint4 v; v.x = st[wb]; v.y = st[wb + 260]; v.z = st[wb + 520]; v.w = st[wb + 780];
      dst[gi] = v;
    }
  }
  __syncthreads();
#pragma unroll
  for (int m = 0; m < 8; ++m) *(uint4*)(st + (w * 8 + m) * 260 + 4 * l) = ppw[m];
  __syncthreads();
  {
    uint4* dst = (uint4*)(PPT + tb);
#pragma unroll
    for (int pass = 0; pass < 8; ++pass) {
      const int gi = pass * 256 + t;
      const int q = gi >> 3, cc = (gi & 7) ^ (q & 7);
      const int wb = cc * 1040 + q;
      uint4 v; v.x = st[wb]; v.y = st[wb + 260]; v.z = st[wb + 520]; v.w = st[wb + 780];
      dst[gi] = v;
    }
  }
  __syncthreads();
  float* red = (float*)st;
#pragma unroll
  for (int j = 0; j < 4; ++j) red[w * 256 + 4 * l + j] = accN[j];
  __syncthreads();
  { const float sn = red[t] + red[256 + t] + red[512 + t] + red[768 + t];
    atomicAdd(&negsum[b * 256 + t], sn); }
  __syncthreads();
#pragma unroll
  for (int j = 0; j < 4; ++j) red[w * 256 + 4 * l + j] = accP[j];
  __syncthreads();
  { const float sq = red[t] + red[256 + t] + red[512 + t] + red[768 + t];
    atomicAdd(&ppsum[b * 256 + t], sq); }
}

// ---------- P2: segmap -> transposed bf16 (raw + binarized from same staging) ----------
__global__ __launch_bounds__(256, 4) void prep_seg(
    const float* __restrict__ seg, ushort_t* __restrict__ SGT, ushort_t* __restrict__ SGB,
    float* __restrict__ segsum, float* __restrict__ nnzb)
{
  __shared__ unsigned int st[32 * 132];   // 16.9 KB
  const int t = threadIdx.x, w = t >> 6, l = t & 63;
  const int side = l >> 5, e0 = (l & 31) * 4;
  const int b = blockIdx.x >> 8, cp = blockIdx.x & 255;
  const size_t base = ((size_t)b * P_ + (size_t)cp * 64) * E_;
  const float* rb = seg + base + (size_t)(w * 16 + side) * E_ + e0;
  float accS[4] = {0.f,0.f,0.f,0.f}; float cnt = 0.f;

  float4 V = *(const float4*)(rb);
#pragma unroll
  for (int m = 0; m < 8; ++m) {
    const int nm = (m < 7) ? m + 1 : 7;
    float4 nV = *(const float4*)(rb + (2 * nm) * E_);
    const float vs[4] = {V.x, V.y, V.z, V.w};
    uint2 own;
    own.x = f2bf(vs[0]) | (f2bf(vs[1]) << 16);
    own.y = f2bf(vs[2]) | (f2bf(vs[3]) << 16);
#pragma unroll
    for (int j = 0; j < 4; ++j) { accS[j] += vs[j]; cnt += (vs[j] > 0.f) ? 1.f : 0.f; }
    uint2 part;
    part.x = (unsigned)__shfl_xor((int)own.x, 32, 64);
    part.y = (unsigned)__shfl_xor((int)own.y, 32, 64);
    unsigned int wa, wb2;
    if (side == 0) {        // own = even p-row; handle e0, e0+1
      wa  = (own.x & 0xFFFFu) | (part.x << 16);
      wb2 = (own.x >> 16) | (part.x & 0xFFFF0000u);
    } else {                // own = odd p-row; handle e0+2, e0+3
      wa  = (part.y & 0xFFFFu) | (own.y << 16);
      wb2 = (part.y >> 16) | (own.y & 0xFFFF0000u);
    }
    uint2 wv; wv.x = wa; wv.y = wb2;
    *(uint2*)(st + (w * 8 + m) * 132 + e0 + side * 2) = wv;
    V = nV;
  }
  const size_t tb = ((size_t)(b * 256 + cp)) * 8192;
  __syncthreads();
  {
    uint4* dT = (uint4*)(SGT + tb);
    uint4* dB = (uint4*)(SGB + tb);
#pragma unroll
    for (int pass = 0; pass < 4; ++pass) {
      const int gi = pass * 256 + t;
      const int e = gi >> 3, cc = (gi & 7) ^ (e & 7);
      const int wb = cc * 528 + e;                        // (cc*4+i)*132 + e
      uint4 v; v.x = st[wb]; v.y = st[wb + 132]; v.z = st[wb + 264]; v.w = st[wb + 396];
      dT[gi] = v;
      uint4 bv;
      bv.x = ((v.x & 0xFFFFu) ? 0x3F80u : 0u) | ((v.x >> 16) ? 0x3F800000u : 0u);
      bv.y = ((v.y & 0xFFFFu) ? 0x3F80u : 0u) | ((v.y >> 16) ? 0x3F800000u : 0u);
      bv.z = ((v.z & 0xFFFFu) ? 0x3F80u : 0u) | ((v.z >> 16) ? 0x3F800000u : 0u);
      bv.w = ((v.w & 0xFFFFu) ? 0x3F80u : 0u) | ((v.w >> 16) ? 0x3F800000u : 0u);
      dB[gi] = bv;
    }
  }
  __syncthreads();
  float* red = (float*)st;
#pragma unroll
  for (int j = 0; j < 4; ++j) red[(w * 2 + side) * 128 + e0 + j] = accS[j];
  __syncthreads();
  if (t < 128) {
    float s = 0.f;
#pragma unroll
    for (int k = 0; k < 8; ++k) s += red[k * 128 + t];
    atomicAdd(&segsum[b * 128 + t], s);
  }
#pragma unroll
  for (int o = 32; o; o >>= 1) cnt += __shfl_xor(cnt, o, 64);
  if (l == 0) atomicAdd(&nnzb[b], cnt);
}

// ---------- GEMM: m97-style, global_load_lds staging, split-K via fp32 atomics ----------
__global__ __launch_bounds__(256, 2) void gemm_mfma(
    const ushort_t* __restrict__ A1T, const ushort_t* __restrict__ PPT,
    const ushort_t* __restrict__ SGT, const ushort_t* __restrict__ SGB,
    float* __restrict__ part)
{
  __shared__ __align__(16) char lds[32768];   // A tile 16KB @0, B tile 16KB @16384
  const int id = blockIdx.x;
  const int ks = id & 15, qt = (id >> 4) & 1, g = (id >> 5) & 1, b = id >> 6;
  const ushort_t* Aall = g ? PPT : A1T;
  const ushort_t* Ball = g ? SGT : SGB;
  const int t = threadIdx.x, l = t & 63, w = t >> 6;
  const int lm = l & 15, quad = l >> 4;
  const int wm = w & 1, wn = w >> 1;
  v4f acc[4][4];
#pragma unroll
  for (int i = 0; i < 4; ++i)
#pragma unroll
    for (int j = 0; j < 4; ++j) acc[i][j] = (v4f)0.f;
  const size_t cp0 = (size_t)b * 256 + ks * 16;
  const char* gA = (const char*)(Aall + cp0 * 16384 + qt * 8192);
  const char* gB = (const char*)(Ball + cp0 * 8192);
  const int off = t * 16;

  for (int it = 0; it < 16; ++it) {
    __syncthreads();
    const char* pa = gA + (size_t)it * 32768;
    const char* pb = gB + (size_t)it * 16384;
    gload16(pa + off,          lds + off);
    gload16(pa + off + 4096,   lds + off + 4096);
    gload16(pa + off + 8192,   lds + off + 8192);
    gload16(pa + off + 12288,  lds + off + 12288);
    gload16(pb + off,          lds + 16384 + off);
    gload16(pb + off + 4096,   lds + 16384 + off + 4096);
    gload16(pb + off + 8192,   lds + 16384 + off + 8192);
    gload16(pb + off + 12288,  lds + 16384 + off + 12288);
    __syncthreads();
#pragma unroll
    for (int k32 = 0; k32 < 2; ++k32) {
      short8 af[4], bf[4];
      const int ach = ((k32 << 2) | quad) ^ (lm & 7);    // un-swizzle -> conflict-free
#pragma unroll
      for (int i = 0; i < 4; ++i) {
        af[i] = *(const short8*)(lds + (wm * 64 + i * 16 + lm) * 128 + ach * 16);
        bf[i] = *(const short8*)(lds + 16384 + (wn * 64 + i * 16 + lm) * 128 + ach * 16);
      }
#pragma unroll
      for (int i = 0; i < 4; ++i)
#pragma unroll
        for (int j = 0; j < 4; ++j)
          acc[i][j] = __builtin_amdgcn_mfma_f32_16x16x32_bf16(af[i], bf[j], acc[i][j], 0, 0, 0);
    }
  }
  float* pout = part + (size_t)(g * 8 + b) * 32768;
#pragma unroll
  for (int i = 0; i < 4; ++i)
#pragma unroll
    for (int r = 0; r < 4; ++r) {
      const int q = qt * 128 + wm * 64 + i * 16 + quad * 4 + r;
#pragma unroll
      for (int j = 0; j < 4; ++j) {
        const int e = wn * 64 + j * 16 + lm;
        atomicAdd(&pout[q * 128 + e], acc[i][j][r]);
      }
    }
}

// ---------- epilogue: all closed-form cost terms ----------
__global__ __launch_bounds__(128) void epilogue(
    const float* __restrict__ part,
    const float* __restrict__ negsum, const float* __restrict__ ppsum,
    const float* __restrict__ segsum, const float* __restrict__ nnzb,
    const float* __restrict__ logits, const float* __restrict__ ppos,
    const float* __restrict__ chol, const float* __restrict__ tpos,
    const float* __restrict__ imgsz, float* __restrict__ out)
{
  const int bq = blockIdx.x;          // b*256 + q
  const int b = bq >> 8;
  const int e = threadIdx.x;
  const int qe = (bq & 255) * 128 + e;
  const float g1 = part[(size_t)b * 32768 + qe];
  const float g2 = part[(size_t)(8 + b) * 32768 + qe];

  const float nnz = fmaxf(nnzb[b], 1.f);
  const float mask_cost = (negsum[bq] + g1) / nnz;
  const float dice = 1.f - (2.f * g2 + 1.f) / (ppsum[bq] + segsum[b * 128 + e] + 1.f);
  const float cls = softplus_f(-logits[bq]);
  const float px = ppos[bq * 2], py = ppos[bq * 2 + 1];
  const float tx = tpos[(b * 128 + e) * 2], ty = tpos[(b * 128 + e) * 2 + 1];
  const float dx = px - tx, dy = py - ty;
  const float ax = fabsf(dx), ay = fabsf(dy);
  const float hx = (ax < 1.f) ? 0.5f * dx * dx : ax - 0.5f;
  const float hy = (ay < 1.f) ? 0.5f * dy * dy : ay - 0.5f;
  const float huber = 0.5f * (hx + hy);
  const float sx = imgsz[b * 2], sy = imgsz[b * 2 + 1];
  const float L00 = chol[bq * 4 + 0], L10 = chol[bq * 4 + 2], L11 = chol[bq * 4 + 3];
  const float d0 = (tx - px) * sx, d1 = (ty - py) * sy;
  const float z0 = d0 / L00;
  const float z1 = (d1 - L10 * z0) / L11;
  const float nll = 0.5f * (z0 * z0 + z1 * z1) + 1.8378770664093453f + __logf(L00) + __logf(L11);
  const float lik = 1.f - __expf(-nll);
  out[bq * 128 + e] = 2.f * cls + 5.f * mask_cost + 5.f * dice + huber + 0.5f * nll + 0.5f * lik;
}

// ---------- launcher ----------
extern "C" void kernel_launch(void* const* d_in, const int* in_sizes, int n_in,
                              void* d_out, int out_size, void* d_ws, size_t ws_size,
                              hipStream_t stream)
{
  (void)in_sizes; (void)n_in; (void)out_size; (void)ws_size;
  const float* logits = (const float*)d_in[0];
  const float* mlv    = (const float*)d_in[1];
  const int*   mask   = (const int*)d_in[2];
  const float* seg    = (const float*)d_in[3];
  const float* ppos   = (const float*)d_in[4];
  const float* chol   = (const float*)d_in[5];
  const float* tpos   = (const float*)d_in[6];
  const float* imgsz  = (const float*)d_in[7];

  char* ws = (char*)d_ws;
  ushort_t* A1T = (ushort_t*)(ws);                 //  67108864 B
  ushort_t* PPT = (ushort_t*)(ws + 67108864);      //  67108864 B
  ushort_t* SGT = (ushort_t*)(ws + 134217728);     //  33554432 B
  ushort_t* SGB = (ushort_t*)(ws + 167772160);     //  33554432 B
  float* part   = (float*)(ws + 201326592);        //   2097152 B  [2][8][256][128]
  float* negsum = (float*)(ws + 203423744);        //   8192 B
  float* ppsum  = (float*)(ws + 203431936);        //   8192 B
  float* segsum = (float*)(ws + 203440128);        //   4096 B
  float* nnzb   = (float*)(ws + 203444224);        //   32 B

  hipMemsetAsync(ws + 201326592, 0, 2117696, stream);
  prep_seg<<<2048, 256, 0, stream>>>(seg, SGT, SGB, segsum, nnzb);
  prep_rows<<<2048, 256, 0, stream>>>(mlv, mask, A1T, PPT, negsum, ppsum);
  gemm_mfma<<<512, 256, 0, stream>>>(A1T, PPT, SGT, SGB, part);
  epilogue<<<2048, 128, 0, stream>>>(part, negsum, ppsum, segsum, nnzb,
                                     logits, ppos, chol, tpos, imgsz, (float*)d_out);
}

// Round 4
// 507.641 us; speedup vs baseline: 1.0310x; 1.0310x over previous
//
#include <hip/hip_runtime.h>
#include <cstdint>
#include <cstddef>

typedef float v4f __attribute__((ext_vector_type(4)));
typedef short short8 __attribute__((ext_vector_type(8)));
typedef unsigned short ushort_t;

constexpr int B_ = 8, P_ = 16384, Q_ = 256, E_ = 128;

// ---------- helpers ----------
__device__ __forceinline__ unsigned int f2bf(float f) {
  unsigned int x = __float_as_uint(f);
  x += 0x7FFFu + ((x >> 16) & 1u);           // round-to-nearest-even
  return x >> 16;
}
__device__ __forceinline__ float bflo(unsigned int u) {   // low bf16 -> f32
  return __uint_as_float(u << 16);
}
__device__ __forceinline__ float bfhi(unsigned int u) {   // high bf16 -> f32
  return __uint_as_float(u & 0xFFFF0000u);
}
__device__ __forceinline__ float softplus_f(float x) {
  return fmaxf(x, 0.f) + __logf(1.f + __expf(-fabsf(x)));
}
__device__ __forceinline__ void gload16(const void* g, void* l) {
  __builtin_amdgcn_global_load_lds((const __attribute__((address_space(1))) void*)g,
                                   (__attribute__((address_space(3))) void*)l,
                                   16, 0, 0);
}

// ---------- P1: row pass, NO cross-lane ops in the hot loop ----------
// Writes A1T[b][cp][q][64p] = bf16(-x*m) and PPT = bf16(ez) (UNNORMALIZED exp),
// 16B-chunk-swizzled (gc = cc ^ (q&7)).  Row softmax sums reduced via LDS at the
// end; stores inv_s[b,p] for prep_seg; ppsum computed in-register from ez*inv_s.
__global__ __launch_bounds__(256, 3) void prep_rows(
    const float* __restrict__ mlv, const int* __restrict__ mask,
    ushort_t* __restrict__ A1T, ushort_t* __restrict__ PPT,
    float* __restrict__ negsum, float* __restrict__ ppsum,
    float* __restrict__ sinvg)
{
  __shared__ unsigned int st[32 * 260];   // 33.3 KB pair-major staging
  __shared__ float red[64 * 65];          // 16.6 KB row partial sums
  __shared__ float red2[256];
  __shared__ float sinv[64];
  const int t = threadIdx.x, w = t >> 6, l = t & 63;
  const int b = blockIdx.x >> 8, cp = blockIdx.x & 255;
  const size_t base = ((size_t)b * P_ + (size_t)cp * 64) * Q_;
  const float* rbase = mlv + base + (size_t)(w * 16) * Q_ + 4 * l;
  const int*   mbase = mask + base + (size_t)(w * 16) * Q_ + 4 * l;
  float accN[4] = {0.f,0.f,0.f,0.f};
  uint4 ezw[8];

  // depth-2 software pipeline
  float4 X0[2], X1[2]; int4 M0[2], M1[2];
  X0[0] = *(const float4*)(rbase);        X1[0] = *(const float4*)(rbase + Q_);
  M0[0] = *(const int4*)(mbase);          M1[0] = *(const int4*)(mbase + Q_);
  X0[1] = *(const float4*)(rbase + 2*Q_); X1[1] = *(const float4*)(rbase + 3*Q_);
  M0[1] = *(const int4*)(mbase + 2*Q_);   M1[1] = *(const int4*)(mbase + 3*Q_);
#pragma unroll
  for (int m = 0; m < 8; ++m) {
    const int s = m & 1;
    const float xs0[4] = {X0[s].x, X0[s].y, X0[s].z, X0[s].w};
    const float xs1[4] = {X1[s].x, X1[s].y, X1[s].z, X1[s].w};
    const int   ms0[4] = {M0[s].x, M0[s].y, M0[s].z, M0[s].w};
    const int   ms1[4] = {M1[s].x, M1[s].y, M1[s].z, M1[s].w};
    if (m < 6) {
      X0[s] = *(const float4*)(rbase + (2*m + 4) * Q_);
      X1[s] = *(const float4*)(rbase + (2*m + 5) * Q_);
      M0[s] = *(const int4*)(mbase + (2*m + 4) * Q_);
      M1[s] = *(const int4*)(mbase + (2*m + 5) * Q_);
    }
    float ps0 = 0.f, ps1 = 0.f;
    unsigned int a1w[4], pw[4];
#pragma unroll
    for (int j = 0; j < 4; ++j) {
      const bool q0 = ms0[j] != 0, q1 = ms1[j] != 0;
      const float e0 = q0 ? __expf(xs0[j]) : 0.f;
      const float e1 = q1 ? __expf(xs1[j]) : 0.f;
      ps0 += e0; ps1 += e1;
      accN[j] += __logf(1.f + e0) + __logf(1.f + e1);     // softplus(x) on masked
      a1w[j] = f2bf(q0 ? -xs0[j] : 0.f) | (f2bf(q1 ? -xs1[j] : 0.f) << 16);
      pw[j]  = f2bf(e0) | (f2bf(e1) << 16);
    }
    ezw[m].x = pw[0]; ezw[m].y = pw[1]; ezw[m].z = pw[2]; ezw[m].w = pw[3];
    uint4 av; av.x = a1w[0]; av.y = a1w[1]; av.z = a1w[2]; av.w = a1w[3];
    *(uint4*)(st + (w * 8 + m) * 260 + 4 * l) = av;       // contiguous b128
    red[(w * 16 + 2*m)     * 65 + l] = ps0;               // 2-way free
    red[(w * 16 + 2*m + 1) * 65 + l] = ps1;
  }
  const size_t tb = ((size_t)(b * 256 + cp)) * 16384;
  __syncthreads();
  // ---- A1 dump (reads st) + row-sum stage (reads red) ----
  {
    uint4* dst = (uint4*)(A1T + tb);
#pragma unroll
    for (int pass = 0; pass < 8; ++pass) {
      const int gi = pass * 256 + t;
      const int q = gi >> 3, cc = (gi & 7) ^ (q & 7);
      const int wb = cc * 1040 + q;                       // (cc*4+i)*260 + q
      uint4 v; v.x = st[wb]; v.y = st[wb + 260]; v.z = st[wb + 520]; v.w = st[wb + 780];
      dst[gi] = v;
    }
  }
  {
    const int row = t >> 2, seg = t & 3;
    float p = 0.f;
#pragma unroll
    for (int k = 0; k < 16; ++k) p += red[row * 65 + seg * 16 + k];
    red2[t] = p;
  }
  __syncthreads();
  if (t < 64) {
    const float sv = red2[4*t] + red2[4*t + 1] + red2[4*t + 2] + red2[4*t + 3];
    const float inv = (sv > 0.f) ? (1.f / sv) : 0.f;
    sinv[t] = inv;
    sinvg[(size_t)(b * 256 + cp) * 64 + t] = inv;
  }
  // ---- EZ staging rewrite ----
#pragma unroll
  for (int m = 0; m < 8; ++m) *(uint4*)(st + (w * 8 + m) * 260 + 4 * l) = ezw[m];
  __syncthreads();
  {
    uint4* dst = (uint4*)(PPT + tb);
#pragma unroll
    for (int pass = 0; pass < 8; ++pass) {
      const int gi = pass * 256 + t;
      const int q = gi >> 3, cc = (gi & 7) ^ (q & 7);
      const int wb = cc * 1040 + q;
      uint4 v; v.x = st[wb]; v.y = st[wb + 260]; v.z = st[wb + 520]; v.w = st[wb + 780];
      dst[gi] = v;
    }
  }
  // ---- ppsum from registers (ez * inv_s), no shfl ----
  float accP[4] = {0.f,0.f,0.f,0.f};
#pragma unroll
  for (int m = 0; m < 8; ++m) {
    const float i0 = sinv[w * 16 + 2*m], i1 = sinv[w * 16 + 2*m + 1];
    const unsigned int pc[4] = {ezw[m].x, ezw[m].y, ezw[m].z, ezw[m].w};
#pragma unroll
    for (int j = 0; j < 4; ++j)
      accP[j] += bflo(pc[j]) * i0 + bfhi(pc[j]) * i1;
  }
  __syncthreads();
  float* fa = (float*)st;
#pragma unroll
  for (int j = 0; j < 4; ++j) {
    fa[w * 256 + 4 * l + j] = accN[j];
    fa[1024 + w * 256 + 4 * l + j] = accP[j];
  }
  __syncthreads();
  {
    const float sn = fa[t] + fa[256 + t] + fa[512 + t] + fa[768 + t];
    const float sq = fa[1024 + t] + fa[1280 + t] + fa[1536 + t] + fa[1792 + t];
    atomicAdd(&negsum[b * 256 + t], sn);
    atomicAdd(&ppsum[b * 256 + t], sq);
  }
}

// ---------- P2: segmap -> SGT' = bf16(segv * inv_s) and SGB = binarized ----------
__global__ __launch_bounds__(256, 4) void prep_seg(
    const float* __restrict__ seg, const float* __restrict__ sinvg,
    ushort_t* __restrict__ SGT, ushort_t* __restrict__ SGB,
    float* __restrict__ segsum, float* __restrict__ nnzb)
{
  __shared__ unsigned int st[32 * 132];   // 16.9 KB
  __shared__ float red[1024];
  __shared__ float sinv[64];
  const int t = threadIdx.x, w = t >> 6, l = t & 63;
  const int h = l >> 5, le = l & 31;
  const int b = blockIdx.x >> 8, cp = blockIdx.x & 255;
  const size_t base = ((size_t)b * P_ + (size_t)cp * 64) * E_;
  if (t < 64) sinv[t] = sinvg[(size_t)(b * 256 + cp) * 64 + t];
  const float* rb = seg + base + (size_t)(w * 16 + h * 2) * E_ + 4 * le;

  float4 V0[4], V1[4];
#pragma unroll
  for (int i = 0; i < 4; ++i) {           // all 8 loads in flight
    V0[i] = *(const float4*)(rb + (i * 4) * E_);
    V1[i] = *(const float4*)(rb + (i * 4 + 1) * E_);
  }
  float accS[4] = {0.f,0.f,0.f,0.f}; float cnt = 0.f;
#pragma unroll
  for (int i = 0; i < 4; ++i) {
    const float v0[4] = {V0[i].x, V0[i].y, V0[i].z, V0[i].w};
    const float v1[4] = {V1[i].x, V1[i].y, V1[i].z, V1[i].w};
    unsigned int pw[4];
#pragma unroll
    for (int j = 0; j < 4; ++j) {
      accS[j] += v0[j] + v1[j];
      cnt += ((v0[j] > 0.f) ? 1.f : 0.f) + ((v1[j] > 0.f) ? 1.f : 0.f);
      pw[j] = f2bf(v0[j]) | (f2bf(v1[j]) << 16);
    }
    uint4 av; av.x = pw[0]; av.y = pw[1]; av.z = pw[2]; av.w = pw[3];
    *(uint4*)(st + (w * 8 + i * 2 + h) * 132 + 4 * le) = av;
  }
  const size_t tb = ((size_t)(b * 256 + cp)) * 8192;
  __syncthreads();
  {
    uint4* dT = (uint4*)(SGT + tb);
    uint4* dB = (uint4*)(SGB + tb);
#pragma unroll
    for (int pass = 0; pass < 4; ++pass) {
      const int gi = pass * 256 + t;
      const int e = gi >> 3, cc = (gi & 7) ^ (e & 7);
      const int wb = cc * 528 + e;                        // (cc*4+i)*132 + e
      unsigned int v[4] = {st[wb], st[wb + 132], st[wb + 264], st[wb + 396]};
      uint4 bv, tv;
      unsigned int tvc[4], bvc[4];
#pragma unroll
      for (int i = 0; i < 4; ++i) {
        const float i0 = sinv[(cc * 4 + i) * 2];
        const float i1 = sinv[(cc * 4 + i) * 2 + 1];
        tvc[i] = f2bf(bflo(v[i]) * i0) | (f2bf(bfhi(v[i]) * i1) << 16);
        bvc[i] = ((v[i] & 0xFFFFu) ? 0x3F80u : 0u) | ((v[i] >> 16) ? 0x3F800000u : 0u);
      }
      tv.x = tvc[0]; tv.y = tvc[1]; tv.z = tvc[2]; tv.w = tvc[3];
      bv.x = bvc[0]; bv.y = bvc[1]; bv.z = bvc[2]; bv.w = bvc[3];
      dT[gi] = tv; dB[gi] = bv;
    }
  }
  __syncthreads();
#pragma unroll
  for (int j = 0; j < 4; ++j) red[(w * 2 + h) * 128 + 4 * le + j] = accS[j];
  __syncthreads();
  if (t < 128) {
    float s = 0.f;
#pragma unroll
    for (int k = 0; k < 8; ++k) s += red[k * 128 + t];
    atomicAdd(&segsum[b * 128 + t], s);
  }
#pragma unroll
  for (int o = 32; o; o >>= 1) cnt += __shfl_xor(cnt, o, 64);
  if (l == 0) atomicAdd(&nnzb[b], cnt);
}

// ---------- GEMM: 256q x 128e tile, 512 threads, split-K via fp32 atomics ----------
// grid = 8b x 2g x 16ks = 256 blocks.  g0: A1T x SGB (mask BCE), g1: PPT x SGT' (dice).
__global__ __launch_bounds__(512, 4) void gemm_mfma(
    const ushort_t* __restrict__ A1T, const ushort_t* __restrict__ PPT,
    const ushort_t* __restrict__ SGT, const ushort_t* __restrict__ SGB,
    float* __restrict__ part)
{
  __shared__ __align__(16) char lds[49152];   // A 32KB @0, B 16KB @32768
  const int id = blockIdx.x;
  const int ks = id & 15, g = (id >> 4) & 1, b = id >> 5;
  const ushort_t* Aall = g ? PPT : A1T;
  const ushort_t* Ball = g ? SGT : SGB;
  const int t = threadIdx.x, l = t & 63, w = t >> 6;
  const int lm = l & 15, quad = l >> 4;
  const int wr = w & 3, wc = w >> 2;
  v4f acc[4][4];
#pragma unroll
  for (int i = 0; i < 4; ++i)
#pragma unroll
    for (int j = 0; j < 4; ++j) acc[i][j] = (v4f)0.f;
  const size_t cp0 = (size_t)b * 256 + ks * 16;
  const char* gA = (const char*)(Aall + cp0 * 16384);
  const char* gB = (const char*)(Ball + cp0 * 8192);
  const int off = t * 16;

  for (int it = 0; it < 16; ++it) {
    __syncthreads();
    const char* pa = gA + (size_t)it * 32768;
    const char* pb = gB + (size_t)it * 16384;
    gload16(pa + off,          lds + off);
    gload16(pa + off + 8192,   lds + off + 8192);
    gload16(pa + off + 16384,  lds + off + 16384);
    gload16(pa + off + 24576,  lds + off + 24576);
    gload16(pb + off,          lds + 32768 + off);
    gload16(pb + off + 8192,   lds + 32768 + off + 8192);
    __syncthreads();
#pragma unroll
    for (int k32 = 0; k32 < 2; ++k32) {
      short8 af[4], bf[4];
      const int ach = ((k32 << 2) | quad) ^ (lm & 7);    // un-swizzle -> conflict-free
#pragma unroll
      for (int i = 0; i < 4; ++i) {
        af[i] = *(const short8*)(lds + (wr * 64 + i * 16 + lm) * 128 + ach * 16);
        bf[i] = *(const short8*)(lds + 32768 + (wc * 64 + i * 16 + lm) * 128 + ach * 16);
      }
#pragma unroll
      for (int i = 0; i < 4; ++i)
#pragma unroll
        for (int j = 0; j < 4; ++j)
          acc[i][j] = __builtin_amdgcn_mfma_f32_16x16x32_bf16(af[i], bf[j], acc[i][j], 0, 0, 0);
    }
  }
  float* pout = part + (size_t)(g * 8 + b) * 32768;
#pragma unroll
  for (int i = 0; i < 4; ++i)
#pragma unroll
    for (int r = 0; r < 4; ++r) {
      const int q = wr * 64 + i * 16 + quad * 4 + r;
#pragma unroll
      for (int j = 0; j < 4; ++j) {
        const int e = wc * 64 + j * 16 + lm;
        atomicAdd(&pout[q * 128 + e], acc[i][j][r]);
      }
    }
}

// ---------- epilogue: all closed-form cost terms ----------
__global__ __launch_bounds__(128) void epilogue(
    const float* __restrict__ part,
    const float* __restrict__ negsum, const float* __restrict__ ppsum,
    const float* __restrict__ segsum, const float* __restrict__ nnzb,
    const float* __restrict__ logits, const float* __restrict__ ppos,
    const float* __restrict__ chol, const float* __restrict__ tpos,
    const float* __restrict__ imgsz, float* __restrict__ out)
{
  const int bq = blockIdx.x;          // b*256 + q
  const int b = bq >> 8;
  const int e = threadIdx.x;
  const int qe = (bq & 255) * 128 + e;
  const float g1 = part[(size_t)b * 32768 + qe];
  const float g2 = part[(size_t)(8 + b) * 32768 + qe];

  const float nnz = fmaxf(nnzb[b], 1.f);
  const float mask_cost = (negsum[bq] + g1) / nnz;
  const float dice = 1.f - (2.f * g2 + 1.f) / (ppsum[bq] + segsum[b * 128 + e] + 1.f);
  const float cls = softplus_f(-logits[bq]);
  const float px = ppos[bq * 2], py = ppos[bq * 2 + 1];
  const float tx = tpos[(b * 128 + e) * 2], ty = tpos[(b * 128 + e) * 2 + 1];
  const float dx = px - tx, dy = py - ty;
  const float ax = fabsf(dx), ay = fabsf(dy);
  const float hx = (ax < 1.f) ? 0.5f * dx * dx : ax - 0.5f;
  const float hy = (ay < 1.f) ? 0.5f * dy * dy : ay - 0.5f;
  const float huber = 0.5f * (hx + hy);
  const float sx = imgsz[b * 2], sy = imgsz[b * 2 + 1];
  const float L00 = chol[bq * 4 + 0], L10 = chol[bq * 4 + 2], L11 = chol[bq * 4 + 3];
  const float d0 = (tx - px) * sx, d1 = (ty - py) * sy;
  const float z0 = d0 / L00;
  const float z1 = (d1 - L10 * z0) / L11;
  const float nll = 0.5f * (z0 * z0 + z1 * z1) + 1.8378770664093453f + __logf(L00) + __logf(L11);
  const float lik = 1.f - __expf(-nll);
  out[bq * 128 + e] = 2.f * cls + 5.f * mask_cost + 5.f * dice + huber + 0.5f * nll + 0.5f * lik;
}

// ---------- launcher ----------
extern "C" void kernel_launch(void* const* d_in, const int* in_sizes, int n_in,
                              void* d_out, int out_size, void* d_ws, size_t ws_size,
                              hipStream_t stream)
{
  (void)in_sizes; (void)n_in; (void)out_size; (void)ws_size;
  const float* logits = (const float*)d_in[0];
  const float* mlv    = (const float*)d_in[1];
  const int*   mask   = (const int*)d_in[2];
  const float* seg    = (const float*)d_in[3];
  const float* ppos   = (const float*)d_in[4];
  const float* chol   = (const float*)d_in[5];
  const float* tpos   = (const float*)d_in[6];
  const float* imgsz  = (const float*)d_in[7];

  char* ws = (char*)d_ws;
  ushort_t* A1T = (ushort_t*)(ws);                 //  67108864 B
  ushort_t* PPT = (ushort_t*)(ws + 67108864);      //  67108864 B  (raw ez)
  ushort_t* SGT = (ushort_t*)(ws + 134217728);     //  33554432 B  (segv * inv_s)
  ushort_t* SGB = (ushort_t*)(ws + 167772160);     //  33554432 B  (binarized)
  float* part   = (float*)(ws + 201326592);        //   2097152 B  [2][8][256][128]
  float* negsum = (float*)(ws + 203423744);        //   8192 B
  float* ppsum  = (float*)(ws + 203431936);        //   8192 B
  float* segsum = (float*)(ws + 203440128);        //   4096 B
  float* nnzb   = (float*)(ws + 203444224);        //   32 B
  float* sinvg  = (float*)(ws + 203448320);        //   524288 B  inv softmax sums

  hipMemsetAsync(ws + 201326592, 0, 2117664, stream);
  prep_rows<<<2048, 256, 0, stream>>>(mlv, mask, A1T, PPT, negsum, ppsum, sinvg);
  prep_seg<<<2048, 256, 0, stream>>>(seg, sinvg, SGT, SGB, segsum, nnzb);
  gemm_mfma<<<256, 512, 0, stream>>>(A1T, PPT, SGT, SGB, part);
  epilogue<<<2048, 128, 0, stream>>>(part, negsum, ppsum, segsum, nnzb,
                                     logits, ppos, chol, tpos, imgsz, (float*)d_out);
}

// Round 5
// 415.014 us; speedup vs baseline: 1.2611x; 1.2232x over previous
//
#include <hip/hip_runtime.h>
#include <cstdint>
#include <cstddef>

typedef float v4f __attribute__((ext_vector_type(4)));
typedef short short8 __attribute__((ext_vector_type(8)));

constexpr int B_ = 8, P_ = 16384, Q_ = 256, E_ = 128;

// ---------- helpers ----------
__device__ __forceinline__ unsigned int f2bf(float f) {
  unsigned int x = __float_as_uint(f);
  x += 0x7FFFu + ((x >> 16) & 1u);           // round-to-nearest-even
  return x >> 16;
}
__device__ __forceinline__ float softplus_f(float x) {
  return fmaxf(x, 0.f) + __logf(1.f + __expf(-fabsf(x)));
}
__device__ __forceinline__ short8 mk8(unsigned a, unsigned b, unsigned c, unsigned d) {
  union { unsigned u[4]; short8 s; } x;
  x.u[0] = a; x.u[1] = b; x.u[2] = c; x.u[3] = d; return x.s;
}
__device__ __forceinline__ float wsum(float v) {
#pragma unroll
  for (int o = 32; o; o >>= 1) v += __shfl_xor(v, o, 64);
  return v;
}

// ---------- fused: prep + both GEMMs, split-K via fp32 atomics ----------
// grid = 8b x 32ks = 256 blocks x 512 threads. Block computes the FULL 256q x 128e
// tile for its 512-p K-chunk (16 steps of 32p). Per step, wave w owns p-rows
// 4w..4w+3 entirely (all 256 q), so softmax row sums are wave-local (butterfly).
// LDS tiles, col-major pair-packed (word = bf16{p even, p odd}):
//   A1t[16][260], EZt[16][260] (q fast, pitch 260), SBt[16][132], STt[16][132].
// Writes: linear b128 (conflict-free). Frag reads: 4x ds_read_b32 stride 260/132
// -> 2 lanes/bank (free). MFMA 16x16x32: k=32 = the whole step.
__global__ __launch_bounds__(512, 2) void fused_all(
    const float* __restrict__ mlv, const int* __restrict__ mask,
    const float* __restrict__ seg, float* __restrict__ part,
    float* __restrict__ negsum, float* __restrict__ ppsum,
    float* __restrict__ segsum, float* __restrict__ nnzb)
{
  __shared__ __align__(16) unsigned int lds[12544];   // 50176 B
  unsigned int* A1t = lds;            // 4160 words
  unsigned int* EZt = lds + 4160;     // 4160
  unsigned int* SBt = lds + 8320;     // 2112
  unsigned int* STt = lds + 10432;    // 2112

  const int t = threadIdx.x, w = t >> 6, l = t & 63;
  const int lm = l & 15, quad = l >> 4;
  const int wr = w & 3, wc = w >> 2;
  const int jj = l >> 5, le = l & 31;
  const int b = blockIdx.x >> 5, ks = blockIdx.x & 31;

  v4f acc0[4][4], acc1[4][4];
#pragma unroll
  for (int i = 0; i < 4; ++i)
#pragma unroll
    for (int j = 0; j < 4; ++j) { acc0[i][j] = (v4f)0.f; acc1[i][j] = (v4f)0.f; }
  float accN[4] = {0.f,0.f,0.f,0.f};
  float accP[4] = {0.f,0.f,0.f,0.f};
  float accS[4] = {0.f,0.f,0.f,0.f};
  float cnt = 0.f;

  const float* mp = mlv + ((size_t)b * P_ + ks * 512 + 4 * w) * Q_ + 4 * l;
  const int*   kp = mask + ((size_t)b * P_ + ks * 512 + 4 * w) * Q_ + 4 * l;
  const float* sp = seg + ((size_t)b * P_ + ks * 512 + 4 * w + 2 * jj) * E_ + 4 * le;

  float4 X[4]; int4 M[4]; float4 S0, S1;
#pragma unroll
  for (int r = 0; r < 4; ++r) {
    X[r] = *(const float4*)(mp + (size_t)r * Q_);
    M[r] = *(const int4*)(kp + (size_t)r * Q_);
  }
  S0 = *(const float4*)(sp);
  S1 = *(const float4*)(sp + E_);

  for (int it = 0; it < 16; ++it) {
    // ---- unpack & compute ----
    float xs[4][4]; int ms[4][4];
#pragma unroll
    for (int r = 0; r < 4; ++r) {
      xs[r][0] = X[r].x; xs[r][1] = X[r].y; xs[r][2] = X[r].z; xs[r][3] = X[r].w;
      ms[r][0] = M[r].x; ms[r][1] = M[r].y; ms[r][2] = M[r].z; ms[r][3] = M[r].w;
    }
    float sv0[4] = {S0.x, S0.y, S0.z, S0.w};
    float sv1[4] = {S1.x, S1.y, S1.z, S1.w};

    // ---- prefetch next step (overlaps everything below) ----
    if (it < 15) {
      mp += 32 * Q_; kp += 32 * Q_; sp += 32 * E_;
#pragma unroll
      for (int r = 0; r < 4; ++r) {
        X[r] = *(const float4*)(mp + (size_t)r * Q_);
        M[r] = *(const int4*)(kp + (size_t)r * Q_);
      }
      S0 = *(const float4*)(sp);
      S1 = *(const float4*)(sp + E_);
    }

    float ez[4][4], rs[4];
#pragma unroll
    for (int r = 0; r < 4; ++r) {
      float s = 0.f;
#pragma unroll
      for (int j = 0; j < 4; ++j) {
        const bool mm = ms[r][j] != 0;
        const float e = mm ? __expf(xs[r][j]) : 0.f;
        ez[r][j] = e; s += e;
        accN[j] += __logf(1.f + e);                    // softplus(x) on masked
      }
      rs[r] = s;
    }
#pragma unroll
    for (int r = 0; r < 4; ++r) rs[r] = wsum(rs[r]);
    float inv[4];
#pragma unroll
    for (int r = 0; r < 4; ++r) inv[r] = (rs[r] > 0.f) ? (1.f / rs[r]) : 0.f;

    unsigned int a1p[2][4], ezp[2][4];
#pragma unroll
    for (int jp = 0; jp < 2; ++jp)
#pragma unroll
      for (int j = 0; j < 4; ++j) {
        const int r0 = 2 * jp, r1 = 2 * jp + 1;
        a1p[jp][j] = f2bf(ms[r0][j] ? -xs[r0][j] : 0.f)
                   | (f2bf(ms[r1][j] ? -xs[r1][j] : 0.f) << 16);
        const float p0 = ez[r0][j] * inv[r0];
        const float p1 = ez[r1][j] * inv[r1];
        accP[j] += p0 + p1;
        ezp[jp][j] = f2bf(p0) | (f2bf(p1) << 16);
      }
    unsigned int sb[4], st_[4];
#pragma unroll
    for (int j = 0; j < 4; ++j) {
      accS[j] += sv0[j] + sv1[j];
      cnt += ((sv0[j] > 0.f) ? 1.f : 0.f) + ((sv1[j] > 0.f) ? 1.f : 0.f);
      sb[j]  = ((sv0[j] > 0.f) ? 0x3F80u : 0u) | ((sv1[j] > 0.f) ? 0x3F800000u : 0u);
      st_[j] = f2bf(sv0[j]) | (f2bf(sv1[j]) << 16);
    }

    __syncthreads();   // previous MFMA phase done reading LDS
    { uint4 v; v.x=a1p[0][0]; v.y=a1p[0][1]; v.z=a1p[0][2]; v.w=a1p[0][3];
      *(uint4*)(A1t + (2*w)     * 260 + 4*l) = v; }
    { uint4 v; v.x=a1p[1][0]; v.y=a1p[1][1]; v.z=a1p[1][2]; v.w=a1p[1][3];
      *(uint4*)(A1t + (2*w + 1) * 260 + 4*l) = v; }
    { uint4 v; v.x=ezp[0][0]; v.y=ezp[0][1]; v.z=ezp[0][2]; v.w=ezp[0][3];
      *(uint4*)(EZt + (2*w)     * 260 + 4*l) = v; }
    { uint4 v; v.x=ezp[1][0]; v.y=ezp[1][1]; v.z=ezp[1][2]; v.w=ezp[1][3];
      *(uint4*)(EZt + (2*w + 1) * 260 + 4*l) = v; }
    { uint4 v; v.x=sb[0]; v.y=sb[1]; v.z=sb[2]; v.w=sb[3];
      *(uint4*)(SBt + (2*w + jj) * 132 + 4*le) = v; }
    { uint4 v; v.x=st_[0]; v.y=st_[1]; v.z=st_[2]; v.w=st_[3];
      *(uint4*)(STt + (2*w + jj) * 132 + 4*le) = v; }
    __syncthreads();

    // ---- MFMA phase: k=32 (whole step) ----
    short8 af0[4], af1[4], bf0[4], bf1[4];
#pragma unroll
    for (int i = 0; i < 4; ++i) {
      const int q_abs = wr * 64 + i * 16 + lm;
      const int c0 = 4 * quad;
      af0[i] = mk8(A1t[c0*260 + q_abs], A1t[(c0+1)*260 + q_abs],
                   A1t[(c0+2)*260 + q_abs], A1t[(c0+3)*260 + q_abs]);
      af1[i] = mk8(EZt[c0*260 + q_abs], EZt[(c0+1)*260 + q_abs],
                   EZt[(c0+2)*260 + q_abs], EZt[(c0+3)*260 + q_abs]);
    }
#pragma unroll
    for (int j = 0; j < 4; ++j) {
      const int e_abs = wc * 64 + j * 16 + lm;
      const int c0 = 4 * quad;
      bf0[j] = mk8(SBt[c0*132 + e_abs], SBt[(c0+1)*132 + e_abs],
                   SBt[(c0+2)*132 + e_abs], SBt[(c0+3)*132 + e_abs]);
      bf1[j] = mk8(STt[c0*132 + e_abs], STt[(c0+1)*132 + e_abs],
                   STt[(c0+2)*132 + e_abs], STt[(c0+3)*132 + e_abs]);
    }
#pragma unroll
    for (int i = 0; i < 4; ++i)
#pragma unroll
      for (int j = 0; j < 4; ++j) {
        acc0[i][j] = __builtin_amdgcn_mfma_f32_16x16x32_bf16(af0[i], bf0[j], acc0[i][j], 0, 0, 0);
        acc1[i][j] = __builtin_amdgcn_mfma_f32_16x16x32_bf16(af1[i], bf1[j], acc1[i][j], 0, 0, 0);
      }
  }

  // ---- reductions ----
  __syncthreads();
  float* fr = (float*)lds;
#pragma unroll
  for (int j = 0; j < 4; ++j) {
    fr[w * 256 + 4 * l + j] = accN[j];
    fr[2048 + w * 256 + 4 * l + j] = accP[j];
    fr[4096 + (2 * w + jj) * 128 + 4 * le + j] = accS[j];
  }
  __syncthreads();
  if (t < 256) {
    float sn = 0.f, sq = 0.f;
#pragma unroll
    for (int k = 0; k < 8; ++k) { sn += fr[k * 256 + t]; sq += fr[2048 + k * 256 + t]; }
    atomicAdd(&negsum[b * 256 + t], sn);
    atomicAdd(&ppsum[b * 256 + t], sq);
  } else if (t < 384) {
    const int e = t - 256;
    float ss = 0.f;
#pragma unroll
    for (int k = 0; k < 16; ++k) ss += fr[4096 + k * 128 + e];
    atomicAdd(&segsum[b * 128 + e], ss);
  }
  cnt = wsum(cnt);
  if (l == 0) atomicAdd(&nnzb[b], cnt);

  // ---- split-K accumulate ----
  float* p0 = part + (size_t)b * 32768;
  float* p1 = part + (size_t)(8 + b) * 32768;
#pragma unroll
  for (int i = 0; i < 4; ++i)
#pragma unroll
    for (int r = 0; r < 4; ++r) {
      const int q = wr * 64 + i * 16 + quad * 4 + r;
#pragma unroll
      for (int j = 0; j < 4; ++j) {
        const int e = wc * 64 + j * 16 + lm;
        atomicAdd(&p0[q * 128 + e], acc0[i][j][r]);
        atomicAdd(&p1[q * 128 + e], acc1[i][j][r]);
      }
    }
}

// ---------- epilogue: all closed-form cost terms ----------
__global__ __launch_bounds__(128) void epilogue(
    const float* __restrict__ part,
    const float* __restrict__ negsum, const float* __restrict__ ppsum,
    const float* __restrict__ segsum, const float* __restrict__ nnzb,
    const float* __restrict__ logits, const float* __restrict__ ppos,
    const float* __restrict__ chol, const float* __restrict__ tpos,
    const float* __restrict__ imgsz, float* __restrict__ out)
{
  const int bq = blockIdx.x;          // b*256 + q
  const int b = bq >> 8;
  const int e = threadIdx.x;
  const int qe = (bq & 255) * 128 + e;
  const float g1 = part[(size_t)b * 32768 + qe];
  const float g2 = part[(size_t)(8 + b) * 32768 + qe];

  const float nnz = fmaxf(nnzb[b], 1.f);
  const float mask_cost = (negsum[bq] + g1) / nnz;
  const float dice = 1.f - (2.f * g2 + 1.f) / (ppsum[bq] + segsum[b * 128 + e] + 1.f);
  const float cls = softplus_f(-logits[bq]);
  const float px = ppos[bq * 2], py = ppos[bq * 2 + 1];
  const float tx = tpos[(b * 128 + e) * 2], ty = tpos[(b * 128 + e) * 2 + 1];
  const float dx = px - tx, dy = py - ty;
  const float ax = fabsf(dx), ay = fabsf(dy);
  const float hx = (ax < 1.f) ? 0.5f * dx * dx : ax - 0.5f;
  const float hy = (ay < 1.f) ? 0.5f * dy * dy : ay - 0.5f;
  const float huber = 0.5f * (hx + hy);
  const float sx = imgsz[b * 2], sy = imgsz[b * 2 + 1];
  const float L00 = chol[bq * 4 + 0], L10 = chol[bq * 4 + 2], L11 = chol[bq * 4 + 3];
  const float d0 = (tx - px) * sx, d1 = (ty - py) * sy;
  const float z0 = d0 / L00;
  const float z1 = (d1 - L10 * z0) / L11;
  const float nll = 0.5f * (z0 * z0 + z1 * z1) + 1.8378770664093453f + __logf(L00) + __logf(L11);
  const float lik = 1.f - __expf(-nll);
  out[bq * 128 + e] = 2.f * cls + 5.f * mask_cost + 5.f * dice + huber + 0.5f * nll + 0.5f * lik;
}

// ---------- launcher ----------
extern "C" void kernel_launch(void* const* d_in, const int* in_sizes, int n_in,
                              void* d_out, int out_size, void* d_ws, size_t ws_size,
                              hipStream_t stream)
{
  (void)in_sizes; (void)n_in; (void)out_size; (void)ws_size;
  const float* logits = (const float*)d_in[0];
  const float* mlv    = (const float*)d_in[1];
  const int*   mask   = (const int*)d_in[2];
  const float* seg    = (const float*)d_in[3];
  const float* ppos   = (const float*)d_in[4];
  const float* chol   = (const float*)d_in[5];
  const float* tpos   = (const float*)d_in[6];
  const float* imgsz  = (const float*)d_in[7];

  char* ws = (char*)d_ws;
  float* part   = (float*)(ws);                    // 2097152 B  [2][8][256][128]
  float* negsum = (float*)(ws + 2097152);          // 8192 B
  float* ppsum  = (float*)(ws + 2105344);          // 8192 B
  float* segsum = (float*)(ws + 2113536);          // 4096 B
  float* nnzb   = (float*)(ws + 2117632);          // 32 B

  hipMemsetAsync(ws, 0, 2117664, stream);
  fused_all<<<256, 512, 0, stream>>>(mlv, mask, seg, part, negsum, ppsum, segsum, nnzb);
  epilogue<<<2048, 128, 0, stream>>>(part, negsum, ppsum, segsum, nnzb,
                                     logits, ppos, chol, tpos, imgsz, (float*)d_out);
}